// Round 5
// baseline (472.401 us; speedup 1.0000x reference)
//
#include <hip/hip_runtime.h>
#include <hip/hip_cooperative_groups.h>
#include <math.h>

namespace cg = cooperative_groups;

#define C_      22      // NUM_CLASSES
#define SKIP_   20
#define NSTEP_  200
#define STEP_   4.0f
#define INL_T_  0.9f
#define LAB_T_  500
#define B_      2
#define H_      480
#define W_      640
#define HW_     (H_ * W_)       // 307200
#define P_      (HW_ / SKIP_)   // 15360

#define TS_       64            // spatial tile side
#define TILES_X_  (W_ / TS_)    // 10
#define NTILES_Y_ 8             // covers y 0..511 (cyr<=479 stays in-bounds)
#define NTILES_   (TILES_X_ * NTILES_Y_)   // 80
#define NPLANES_  (B_ * (C_ - 1))          // 42 live planes (c=0 dead)
#define NPT_      (NPLANES_ * NTILES_)     // 3360 plane-tiles
#define CAP_      1024                     // records per plane-tile

#define SUB_A_    4                        // ray segments per point
#define SEG_LEN_  (NSTEP_ / SUB_A_)        // 50
#define PA_BLOCKS_    ((B_ * P_ * SUB_A_) / 256)  // 480 virtual blocks
#define COUNT_BLOCKS_ ((B_ * HW_) / 256)          // 2400 virtual blocks
#define NB_       512                      // cooperative grid (2 blocks/CU — safe co-residency)
// zeroed scratch words: cnt 13440 + key 88 + counts 44 + z_sum 44 + n_inl 44
#define ZERO_WORDS_ 13660

__device__ __forceinline__ void emit_run(unsigned int* cnt, uint4* lists, int pt,
                                         int xi, int yi, int i0, int i1,
                                         float dnx, float dny) {
    unsigned slot = atomicAdd(&cnt[pt], 1u);
    if (slot < CAP_) {
        uint4 r;
        r.x = (unsigned)xi | ((unsigned)yi << 16);
        r.y = (unsigned)i0 | ((unsigned)i1 << 8);
        r.z = __float_as_uint(dnx);
        r.w = __float_as_uint(dny);
        lists[(size_t)pt * CAP_ + slot] = r;
    }
}

__global__ __launch_bounds__(256) void fused_kernel(
        const int* __restrict__ label, const float* __restrict__ vp,
        const float* __restrict__ extents, const float* __restrict__ meta,
        float* __restrict__ out,
        unsigned int* __restrict__ cnt, uint4* __restrict__ lists,
        int* __restrict__ counts, unsigned long long* __restrict__ key,
        float* __restrict__ z_sum, float* __restrict__ n_inl,
        unsigned int* __restrict__ zero_base) {
    cg::grid_group grid = cg::this_grid();
    __shared__ unsigned int tile[TS_ * TS_];   // 16 KB
    __shared__ unsigned int sv[256];
    __shared__ int          si[256];
    __shared__ int   h[C_];
    __shared__ float zs[C_], ns[C_];

    // ---------- phase 1: zero scratch (replaces hipMemsetAsync) ----------
    int gtid = blockIdx.x * 256 + threadIdx.x;
    if (gtid < ZERO_WORDS_) zero_base[gtid] = 0u;
    grid.sync();

    // ---------- phase 2: ray->tile-run binning + label histogram ----------
    for (int vb = blockIdx.x; vb < PA_BLOCKS_ + COUNT_BLOCKS_; vb += NB_) {
        if (vb < PA_BLOCKS_) {
            int tid = vb * 256 + threadIdx.x;
            int pt  = tid >> 2;
            int sub = tid & 3;
            int b   = pt / P_;
            int pi  = pt - b * P_;
            int idx = pi * SKIP_;
            int lab = label[b * HW_ + idx];
            if (lab > 0) {
                int xi = idx % W_, yi = idx / W_;
                float xs = (float)xi, ys = (float)yi;
                const float* s = vp + ((size_t)(b * HW_ + idx) * (C_ * 3)) + lab * 3;
                float dx = s[0], dy = s[1];
                float nrm = sqrtf(__fadd_rn(__fmul_rn(dx, dx), __fmul_rn(dy, dy))) + 1e-9f;
                float dnx = dx / nrm, dny = dy / nrm;
                int base = (b * (C_ - 1) + (lab - 1)) * NTILES_;
                int curTile = -1, runStart = 0;
                int iBeg = sub * SEG_LEN_, iEnd = iBeg + SEG_LEN_;
                for (int i = iBeg; i < iEnd; ++i) {
                    float t = (float)(i + 1) * STEP_;
                    float cx = __fadd_rn(xs, __fmul_rn(dnx, t));   // mul-then-add, no fma
                    float cy = __fadd_rn(ys, __fmul_rn(dny, t));
                    float cxr = rintf(cx);                          // round-half-even == jnp.round
                    float cyr = rintf(cy);
                    int tl2 = -1;
                    if (cxr >= 0.0f && cxr <= (float)(W_ - 1) && cyr >= 0.0f && cyr <= (float)(H_ - 1))
                        tl2 = (((int)cyr) >> 6) * TILES_X_ + (((int)cxr) >> 6);
                    if (tl2 != curTile) {
                        if (curTile >= 0)
                            emit_run(cnt, lists, base + curTile, xi, yi, runStart, i - 1, dnx, dny);
                        curTile = tl2;
                        runStart = i;
                    }
                }
                if (curTile >= 0)
                    emit_run(cnt, lists, base + curTile, xi, yi, runStart, iEnd - 1, dnx, dny);
            }
        } else {
            int cb  = vb - PA_BLOCKS_;
            const int bpb = HW_ / 256;
            int b   = cb / bpb;
            int off = (cb % bpb) * 256 + threadIdx.x;
            if (threadIdx.x < C_) h[threadIdx.x] = 0;
            __syncthreads();
            int lab = label[b * HW_ + off];
            atomicAdd(&h[lab], 1);
            __syncthreads();
            if (threadIdx.x < C_) {
                int v = h[threadIdx.x];
                if (v) atomicAdd(&counts[b * C_ + threadIdx.x], v);
            }
            __syncthreads();
        }
    }
    grid.sync();

    // ---------- phase 3: LDS tile rasterize + argmax, key merge ----------
    // key = (count << 32) | (0xFFFFFFFF - idx): max key == max count, tie -> min idx.
    for (int pt = blockIdx.x; pt < NPT_; pt += NB_) {
        {   // zero tile with uint4 stores
            uint4* t4 = (uint4*)tile;
            #pragma unroll
            for (int j = 0; j < 4; ++j)
                t4[threadIdx.x + j * 256] = make_uint4(0u, 0u, 0u, 0u);
        }
        __syncthreads();
        int p  = pt / NTILES_;
        int tl = pt % NTILES_;
        int b = p / (C_ - 1);
        int c = p % (C_ - 1) + 1;
        int x0 = (tl % TILES_X_) * TS_;
        int y0 = (tl / TILES_X_) * TS_;
        int n = (int)cnt[pt];
        if (n > CAP_) n = CAP_;
        const uint4* lst = lists + (size_t)pt * CAP_;
        int hwv = threadIdx.x >> 5, ln = threadIdx.x & 31;   // half-wave per record
        for (int r = hwv; r < n; r += 8) {
            uint4 rec = lst[r];
            int i0 = (int)(rec.y & 0xFFu), i1 = (int)((rec.y >> 8) & 0xFFu);
            float xs = (float)(rec.x & 0xFFFFu);
            float ys = (float)(rec.x >> 16);
            float dnx = __uint_as_float(rec.z);
            float dny = __uint_as_float(rec.w);
            for (int i = i0 + ln; i <= i1; i += 32) {
                float t = (float)(i + 1) * STEP_;
                float cx = __fadd_rn(xs, __fmul_rn(dnx, t));   // identical ops as phase 2
                float cy = __fadd_rn(ys, __fmul_rn(dny, t));
                int lx = (int)rintf(cx) - x0;
                int ly = (int)rintf(cy) - y0;
                atomicAdd(&tile[ly * TS_ + lx], 1u);           // in-tile by construction
            }
        }
        __syncthreads();
        // conflict-free strided scan: lane reads tile[t + 256*j] (bank = t%32 for all j)
        unsigned bv = tile[threadIdx.x];
        int bi = threadIdx.x;
        #pragma unroll
        for (int j = 1; j < 16; ++j) {
            int ix = threadIdx.x + j * 256;
            unsigned v = tile[ix];
            if (v > bv) { bv = v; bi = ix; }   // strict > keeps smallest ix per thread
        }
        sv[threadIdx.x] = bv; si[threadIdx.x] = bi;
        __syncthreads();
        for (int s = 128; s > 0; s >>= 1) {
            if (threadIdx.x < s) {
                unsigned ov = sv[threadIdx.x + s]; int oi = si[threadIdx.x + s];
                if (ov > sv[threadIdx.x] || (ov == sv[threadIdx.x] && oi < si[threadIdx.x])) {
                    sv[threadIdx.x] = ov; si[threadIdx.x] = oi;
                }
            }
            __syncthreads();
        }
        if (threadIdx.x == 0) {
            int ly = si[0] >> 6, lx = si[0] & 63;
            unsigned gidx = (unsigned)((y0 + ly) * W_ + (x0 + lx));
            unsigned long long k = ((unsigned long long)sv[0] << 32)
                                 | (unsigned long long)(0xFFFFFFFFu - gidx);
            atomicMax(&key[b * C_ + c], k);
        }
        __syncthreads();
    }
    grid.sync();

    // ---------- phase 4: inlier z/count accumulation ----------
    for (int vb = blockIdx.x; vb < (B_ * P_) / 256; vb += NB_) {
        const int bpb = P_ / 256;
        int b  = vb / bpb;
        int pi = (vb % bpb) * 256 + threadIdx.x;
        if (threadIdx.x < C_) { zs[threadIdx.x] = 0.0f; ns[threadIdx.x] = 0.0f; }
        __syncthreads();
        int idx = pi * SKIP_;
        int lab = label[b * HW_ + idx];
        if (lab > 0) {
            float ys = (float)(idx / W_);
            float xs = (float)(idx % W_);
            const float* s = vp + ((size_t)(b * HW_ + idx) * (C_ * 3)) + lab * 3;
            float dx = s[0], dy = s[1], z = s[2];
            float nrm = sqrtf(__fadd_rn(__fmul_rn(dx, dx), __fmul_rn(dy, dy))) + 1e-9f;
            float dnx = dx / nrm, dny = dy / nrm;
            unsigned long long k = key[b * C_ + lab];
            int pkv = (int)(0xFFFFFFFFu - (unsigned int)(k & 0xFFFFFFFFull));
            float pkx = (float)(pkv % W_), pky = (float)(pkv / W_);
            float dvx = __fsub_rn(pkx, xs), dvy = __fsub_rn(pky, ys);
            float nrm2 = sqrtf(__fadd_rn(__fmul_rn(dvx, dvx), __fmul_rn(dvy, dvy))) + 1e-9f;
            dvx /= nrm2; dvy /= nrm2;
            float dot = __fadd_rn(__fmul_rn(dnx, dvx), __fmul_rn(dny, dvy));
            if (dot > INL_T_) {
                atomicAdd(&zs[lab], z);
                atomicAdd(&ns[lab], 1.0f);
            }
        }
        __syncthreads();
        if (threadIdx.x < C_) {
            if (ns[threadIdx.x] != 0.0f) {
                atomicAdd(&z_sum[b * C_ + threadIdx.x], zs[threadIdx.x]);
                atomicAdd(&n_inl[b * C_ + threadIdx.x], ns[threadIdx.x]);
            }
        }
        __syncthreads();
    }
    grid.sync();

    // ---------- phase 5: finalize rois + pose ----------
    if (blockIdx.x == 0 && threadIdx.x < B_ * C_) {
        int t = threadIdx.x;
        int b = t / C_, c = t % C_;
        float* o = out + t * 14;
        bool valid = (counts[t] >= LAB_T_) && (c > 0);
        if (!valid) {
            #pragma unroll
            for (int k2 = 0; k2 < 14; ++k2) o[k2] = 0.0f;
        } else {
            float depth = z_sum[t] / fmaxf(n_inl[t], 1.0f);
            float z_safe = (fabsf(depth) > 0.001f) ? depth : 1.0f;
            float fx = meta[b * 48 + 0];
            float fy = meta[b * 48 + 4];
            const float* e = extents + c * 3;
            float diam = sqrtf(e[0]*e[0] + e[1]*e[1] + e[2]*e[2]);
            unsigned long long k = key[t];
            float vmax = (float)(unsigned int)(k >> 32);
            int pkv = (int)(0xFFFFFFFFu - (unsigned int)(k & 0xFFFFFFFFull));
            float pkx = (float)(pkv % W_), pky = (float)(pkv / W_);
            float half_w = ((0.5f * diam) * fx) / z_safe;
            float half_h = ((0.5f * diam) * fy) / z_safe;
            o[0] = (float)b;
            o[1] = (float)c;
            o[2] = pkx - half_w;
            o[3] = pky - half_h;
            o[4] = pkx + half_w;
            o[5] = pky + half_h;
            o[6] = vmax;
            const float* Ki = meta + b * 48 + 9;   // Kinv row-major 3x3
            float rx = Ki[0]*pkx + Ki[1]*pky + Ki[2];
            float ry = Ki[3]*pkx + Ki[4]*pky + Ki[5];
            float rz = Ki[6]*pkx + Ki[7]*pky + Ki[8];
            o[7]  = 1.0f;
            o[8]  = 0.0f;
            o[9]  = 0.0f;
            o[10] = 0.0f;
            o[11] = depth * rx;
            o[12] = depth * ry;
            o[13] = depth * rz;
        }
    }
}

extern "C" void kernel_launch(void* const* d_in, const int* in_sizes, int n_in,
                              void* d_out, int out_size, void* d_ws, size_t ws_size,
                              hipStream_t stream) {
    const int*   label   = (const int*)d_in[0];    // (B,H,W) int32
    const float* vp      = (const float*)d_in[1];  // (B,H,W,66) f32
    const float* extents = (const float*)d_in[2];  // (22,3) f32
    const float* meta    = (const float*)d_in[4];  // (B,48) f32
    float* out = (float*)d_out;                    // (B,C,14) = 616 f32

    char* ws = (char*)d_ws;
    size_t off = 0;
    unsigned int* cnt = (unsigned int*)(ws + off);             off += NPT_ * sizeof(unsigned int);      // 53760 B
    unsigned long long* key = (unsigned long long*)(ws + off); off += B_ * C_ * sizeof(unsigned long long); // +352
    int*   counts = (int*)(ws + off);   off += B_ * C_ * sizeof(int);
    float* z_sum  = (float*)(ws + off); off += B_ * C_ * sizeof(float);
    float* n_inl  = (float*)(ws + off); off += B_ * C_ * sizeof(float);
    // off == ZERO_WORDS_*4 == 54640, 16B-aligned
    uint4* lists = (uint4*)(ws + off);                         // 3360*1024*16B = 55 MB (uninitialized ok)
    unsigned int* zero_base = (unsigned int*)d_ws;

    void* args[] = { (void*)&label, (void*)&vp, (void*)&extents, (void*)&meta, (void*)&out,
                     (void*)&cnt, (void*)&lists, (void*)&counts, (void*)&key,
                     (void*)&z_sum, (void*)&n_inl, (void*)&zero_base };
    hipLaunchCooperativeKernel((void*)fused_kernel, dim3(NB_), dim3(256), args, 0, stream);
}

// Round 8
// 269.456 us; speedup vs baseline: 1.7532x; 1.7532x over previous
//
#include <hip/hip_runtime.h>
#include <math.h>

#define C_      22      // NUM_CLASSES
#define SKIP_   20
#define NSTEP_  200
#define STEP_   4.0f
#define INL_T_  0.9f
#define LAB_T_  500
#define B_      2
#define H_      480
#define W_      640
#define HW_     (H_ * W_)       // 307200
#define P_      (HW_ / SKIP_)   // 15360

#define TS_       64            // spatial tile side
#define TILES_X_  (W_ / TS_)    // 10
#define NTILES_Y_ 8             // covers y 0..511 (cyr<=479 keeps in-bounds)
#define NTILES_   (TILES_X_ * NTILES_Y_)   // 80
#define NPLANES_  (B_ * (C_ - 1))          // 42 live planes (c=0 dead)
#define NPT_      (NPLANES_ * NTILES_)     // 3360 plane-tiles
#define CAP_      2048                     // records per plane-tile

#define SUB_A_    8                        // ray segments per point
#define SEG_LEN_  (NSTEP_ / SUB_A_)        // 25
#define PA_BLOCKS_    ((B_ * P_ * SUB_A_) / 256)  // 960
#define COUNT_BLOCKS_ ((B_ * HW_) / 256)          // 2400
#define INL_BLOCKS_   ((B_ * P_) / 256)           // 120

#define KEY_INIT_ 0x00000000FFFFFFFFull    // (count 0, idx 0) under the key encoding

// -------- pass A: ray->tile-run binning (+ fused label histogram + key init) --------
__device__ __forceinline__ void emit_run(unsigned int* cnt, uint4* lists, int pt,
                                         int xi, int yi, int i0, int i1,
                                         float dnx, float dny) {
    unsigned slot = atomicAdd(&cnt[pt], 1u);
    if (slot < CAP_) {
        uint4 r;
        r.x = (unsigned)xi | ((unsigned)yi << 16);
        r.y = (unsigned)i0 | ((unsigned)i1 << 8);
        r.z = __float_as_uint(dnx);
        r.w = __float_as_uint(dny);
        lists[(size_t)pt * CAP_ + slot] = r;
    }
}

__global__ __launch_bounds__(256) void binray_count_kernel(const int* __restrict__ label,
                                                           const float* __restrict__ vp,
                                                           unsigned int* __restrict__ cnt,
                                                           uint4* __restrict__ lists,
                                                           int* __restrict__ counts,
                                                           unsigned long long* __restrict__ key) {
    if (blockIdx.x < PA_BLOCKS_) {
        int tid = blockIdx.x * 256 + threadIdx.x;   // 0 .. B_*P_*SUB_A_-1
        int pt  = tid >> 3;                          // point id
        int sub = tid & 7;
        int b   = pt / P_;
        int pi  = pt - b * P_;
        int idx = pi * SKIP_;
        int lab = label[b * HW_ + idx];
        if (lab <= 0) return;
        int xi = idx % W_, yi = idx / W_;
        float xs = (float)xi, ys = (float)yi;
        const float* s = vp + ((size_t)(b * HW_ + idx) * (C_ * 3)) + lab * 3;
        float dx = s[0], dy = s[1];
        float nrm = sqrtf(__fadd_rn(__fmul_rn(dx, dx), __fmul_rn(dy, dy))) + 1e-9f;
        float dnx = dx / nrm, dny = dy / nrm;
        int base = (b * (C_ - 1) + (lab - 1)) * NTILES_;
        int curTile = -1, runStart = 0;
        bool entered = false;
        int iBeg = sub * SEG_LEN_, iEnd = iBeg + SEG_LEN_;
        for (int i = iBeg; i < iEnd; ++i) {
            float t = (float)(i + 1) * STEP_;
            float cx = __fadd_rn(xs, __fmul_rn(dnx, t));   // mul-then-add, no fma
            float cy = __fadd_rn(ys, __fmul_rn(dny, t));
            float cxr = rintf(cx);                          // round-half-even == jnp.round
            float cyr = rintf(cy);
            int tl2 = -1;
            if (cxr >= 0.0f && cxr <= (float)(W_ - 1) && cyr >= 0.0f && cyr <= (float)(H_ - 1))
                tl2 = (((int)cyr) >> 6) * TILES_X_ + (((int)cxr) >> 6);
            if (tl2 != curTile) {
                if (curTile >= 0)
                    emit_run(cnt, lists, base + curTile, xi, yi, runStart, i - 1, dnx, dny);
                curTile = tl2;
                runStart = i;
            }
            if (tl2 >= 0) entered = true;
            else if (entered) break;   // in-bounds i-set is an interval (monotone rintf of linear path)
        }
        if (curTile >= 0)
            emit_run(cnt, lists, base + curTile, xi, yi, runStart, iEnd - 1, dnx, dny);
    } else {
        // ---- label histogram (+ one block initializes key) ----
        __shared__ int h[C_];
        int cb  = blockIdx.x - PA_BLOCKS_;
        if (cb == 0 && threadIdx.x < B_ * C_)
            key[threadIdx.x] = KEY_INIT_;   // visible to raster kernel via stream ordering
        const int bpb = HW_ / 256;
        int b   = cb / bpb;
        int off = (cb % bpb) * 256 + threadIdx.x;
        if (threadIdx.x < C_) h[threadIdx.x] = 0;
        __syncthreads();
        int lab = label[b * HW_ + off];
        atomicAdd(&h[lab], 1);
        __syncthreads();
        if (threadIdx.x < C_) {
            int v = h[threadIdx.x];
            if (v) atomicAdd(&counts[b * C_ + threadIdx.x], v);
        }
    }
}

// -------- pass B: u16-packed LDS tile rasterize + argmax + key merge --------
// key = (count << 32) | (0xFFFFFFFF - idx): max key == max count, tie -> min idx.
// key pre-initialized to (count 0, idx 0), so empty tiles skip their atomicMax.
__global__ __launch_bounds__(256) void raster_argmax_kernel(const unsigned int* __restrict__ cnt,
                                                            const uint4* __restrict__ lists,
                                                            unsigned long long* __restrict__ key) {
    __shared__ unsigned int tile[TS_ * TS_ / 2];   // u16-packed, 8 KB
    __shared__ unsigned int sv[256];
    __shared__ int          si[256];
    int pt = blockIdx.x;                 // 0..3359
    int n = (int)cnt[pt];
    if (n == 0) return;                  // empty tile: cannot beat key init
    if (n > CAP_) n = CAP_;
    {   // zero tile with uint4 stores (2 per thread)
        uint4* t4 = (uint4*)tile;
        t4[threadIdx.x]       = make_uint4(0u, 0u, 0u, 0u);
        t4[threadIdx.x + 256] = make_uint4(0u, 0u, 0u, 0u);
    }
    __syncthreads();
    int p  = pt / NTILES_;
    int tl = pt % NTILES_;
    int b = p / (C_ - 1);
    int c = p % (C_ - 1) + 1;
    int x0 = (tl % TILES_X_) * TS_;
    int y0 = (tl / TILES_X_) * TS_;
    const uint4* lst = lists + (size_t)pt * CAP_;
    int hwv = threadIdx.x >> 5, ln = threadIdx.x & 31;   // half-wave per record
    for (int r = hwv; r < n; r += 8) {
        uint4 rec = lst[r];
        int i0 = (int)(rec.y & 0xFFu), i1 = (int)((rec.y >> 8) & 0xFFu);
        float xs = (float)(rec.x & 0xFFFFu);
        float ys = (float)(rec.x >> 16);
        float dnx = __uint_as_float(rec.z);
        float dny = __uint_as_float(rec.w);
        for (int i = i0 + ln; i <= i1; i += 32) {
            float t = (float)(i + 1) * STEP_;
            float cx = __fadd_rn(xs, __fmul_rn(dnx, t));   // identical ops as pass A
            float cy = __fadd_rn(ys, __fmul_rn(dny, t));
            int lx = (int)rintf(cx) - x0;
            int ly = (int)rintf(cy) - y0;
            int cell = ly * TS_ + lx;                      // in-tile by construction
            atomicAdd(&tile[cell >> 1], 1u << ((cell & 1) * 16));
        }
    }
    __syncthreads();
    // conflict-free strided scan: word ix = tid + 256*j (bank = tid%32), cells 2ix,2ix+1
    unsigned bv = 0u; int bi = 0;
    {
        unsigned w0 = tile[threadIdx.x];
        bv = w0 & 0xFFFFu; bi = threadIdx.x * 2;
        unsigned hi = w0 >> 16;
        if (hi > bv) { bv = hi; bi = threadIdx.x * 2 + 1; }
    }
    #pragma unroll
    for (int j = 1; j < 8; ++j) {
        int ix = threadIdx.x + j * 256;
        unsigned w = tile[ix];
        unsigned lo = w & 0xFFFFu, hi = w >> 16;
        if (lo > bv) { bv = lo; bi = ix * 2; }
        if (hi > bv) { bv = hi; bi = ix * 2 + 1; }
    }
    sv[threadIdx.x] = bv; si[threadIdx.x] = bi;
    __syncthreads();
    for (int s = 128; s > 0; s >>= 1) {
        if (threadIdx.x < s) {
            unsigned ov = sv[threadIdx.x + s]; int oi = si[threadIdx.x + s];
            if (ov > sv[threadIdx.x] || (ov == sv[threadIdx.x] && oi < si[threadIdx.x])) {
                sv[threadIdx.x] = ov; si[threadIdx.x] = oi;
            }
        }
        __syncthreads();
    }
    if (threadIdx.x == 0) {
        int ly = si[0] >> 6, lx = si[0] & 63;
        unsigned gidx = (unsigned)((y0 + ly) * W_ + (x0 + lx));
        unsigned long long k = ((unsigned long long)sv[0] << 32)
                             | (unsigned long long)(0xFFFFFFFFu - gidx);
        atomicMax(&key[b * C_ + c], k);
    }
}

// -------- inlier z/count accumulation (plain, no fusion) --------
__global__ __launch_bounds__(256) void inlier_kernel(const int* __restrict__ label,
                                                     const float* __restrict__ vp,
                                                     const unsigned long long* __restrict__ key,
                                                     float* __restrict__ z_sum,
                                                     float* __restrict__ n_inl) {
    __shared__ float zs[C_];
    __shared__ float ns[C_];
    const int bpb = P_ / 256;
    int b  = blockIdx.x / bpb;
    int pi = (blockIdx.x % bpb) * 256 + threadIdx.x;
    if (threadIdx.x < C_) { zs[threadIdx.x] = 0.0f; ns[threadIdx.x] = 0.0f; }
    __syncthreads();
    int idx = pi * SKIP_;
    int lab = label[b * HW_ + idx];
    if (lab > 0) {
        float ys = (float)(idx / W_);
        float xs = (float)(idx % W_);
        const float* s = vp + ((size_t)(b * HW_ + idx) * (C_ * 3)) + lab * 3;
        float dx = s[0], dy = s[1], z = s[2];
        float nrm = sqrtf(__fadd_rn(__fmul_rn(dx, dx), __fmul_rn(dy, dy))) + 1e-9f;
        float dnx = dx / nrm, dny = dy / nrm;
        unsigned long long k = key[b * C_ + lab];
        int pkv = (int)(0xFFFFFFFFu - (unsigned int)(k & 0xFFFFFFFFull));
        float pkx = (float)(pkv % W_), pky = (float)(pkv / W_);
        float dvx = __fsub_rn(pkx, xs), dvy = __fsub_rn(pky, ys);
        float nrm2 = sqrtf(__fadd_rn(__fmul_rn(dvx, dvx), __fmul_rn(dvy, dvy))) + 1e-9f;
        dvx /= nrm2; dvy /= nrm2;
        float dot = __fadd_rn(__fmul_rn(dnx, dvx), __fmul_rn(dny, dvy));
        if (dot > INL_T_) {
            atomicAdd(&zs[lab], z);
            atomicAdd(&ns[lab], 1.0f);
        }
    }
    __syncthreads();
    if (threadIdx.x < C_) {
        if (ns[threadIdx.x] != 0.0f) {
            atomicAdd(&z_sum[b * C_ + threadIdx.x], zs[threadIdx.x]);
            atomicAdd(&n_inl[b * C_ + threadIdx.x], ns[threadIdx.x]);
        }
    }
}

// -------- finalize rois + pose --------
__global__ __launch_bounds__(64) void finalize_kernel(const int* __restrict__ counts,
                                                      const unsigned long long* __restrict__ key,
                                                      const float* __restrict__ z_sum,
                                                      const float* __restrict__ n_inl,
                                                      const float* __restrict__ extents,
                                                      const float* __restrict__ meta,
                                                      float* __restrict__ out) {
    int t = threadIdx.x;
    if (t >= B_ * C_) return;
    int b = t / C_, c = t % C_;
    float* o = out + t * 14;
    bool valid = (counts[t] >= LAB_T_) && (c > 0);
    if (!valid) {
        #pragma unroll
        for (int k2 = 0; k2 < 14; ++k2) o[k2] = 0.0f;
        return;
    }
    float depth = z_sum[t] / fmaxf(n_inl[t], 1.0f);
    float z_safe = (fabsf(depth) > 0.001f) ? depth : 1.0f;
    float fx = meta[b * 48 + 0];
    float fy = meta[b * 48 + 4];
    const float* e = extents + c * 3;
    float diam = sqrtf(e[0]*e[0] + e[1]*e[1] + e[2]*e[2]);
    unsigned long long k = key[t];
    float vmax = (float)(unsigned int)(k >> 32);
    int pkv = (int)(0xFFFFFFFFu - (unsigned int)(k & 0xFFFFFFFFull));
    float pkx = (float)(pkv % W_), pky = (float)(pkv / W_);
    float half_w = ((0.5f * diam) * fx) / z_safe;
    float half_h = ((0.5f * diam) * fy) / z_safe;
    o[0] = (float)b;
    o[1] = (float)c;
    o[2] = pkx - half_w;
    o[3] = pky - half_h;
    o[4] = pkx + half_w;
    o[5] = pky + half_h;
    o[6] = vmax;
    const float* Ki = meta + b * 48 + 9;   // Kinv row-major 3x3
    float rx = Ki[0]*pkx + Ki[1]*pky + Ki[2];
    float ry = Ki[3]*pkx + Ki[4]*pky + Ki[5];
    float rz = Ki[6]*pkx + Ki[7]*pky + Ki[8];
    o[7]  = 1.0f;
    o[8]  = 0.0f;
    o[9]  = 0.0f;
    o[10] = 0.0f;
    o[11] = depth * rx;
    o[12] = depth * ry;
    o[13] = depth * rz;
}

extern "C" void kernel_launch(void* const* d_in, const int* in_sizes, int n_in,
                              void* d_out, int out_size, void* d_ws, size_t ws_size,
                              hipStream_t stream) {
    const int*   label   = (const int*)d_in[0];    // (B,H,W) int32
    const float* vp      = (const float*)d_in[1];  // (B,H,W,66) f32
    const float* extents = (const float*)d_in[2];  // (22,3) f32
    const float* meta    = (const float*)d_in[4];  // (B,48) f32
    float* out = (float*)d_out;                    // (B,C,14) = 616 f32

    char* ws = (char*)d_ws;
    size_t off = 0;
    unsigned int* cnt = (unsigned int*)(ws + off);  off += NPT_ * sizeof(unsigned int);   // 53760
    int*   counts = (int*)(ws + off);   off += B_ * C_ * sizeof(int);                     // +176
    float* z_sum  = (float*)(ws + off); off += B_ * C_ * sizeof(float);                   // +176
    float* n_inl  = (float*)(ws + off); off += B_ * C_ * sizeof(float);                   // +176
    size_t zero_bytes = off;                        // 54288 B -> memset 0x00
    off = (off + 15) & ~(size_t)15;                 // align 16
    unsigned long long* key = (unsigned long long*)(ws + off);  // init'd by binray kernel
    off += B_ * C_ * sizeof(unsigned long long);
    off = (off + 15) & ~(size_t)15;
    uint4* lists = (uint4*)(ws + off);              // 3360*2048*16B = 110 MB (uninitialized ok)

    hipMemsetAsync(d_ws, 0, zero_bytes, stream);

    binray_count_kernel<<<PA_BLOCKS_ + COUNT_BLOCKS_, 256, 0, stream>>>(label, vp, cnt, lists, counts, key);
    raster_argmax_kernel<<<NPT_, 256, 0, stream>>>(cnt, lists, key);
    inlier_kernel<<<INL_BLOCKS_, 256, 0, stream>>>(label, vp, key, z_sum, n_inl);
    finalize_kernel<<<1, 64, 0, stream>>>(counts, key, z_sum, n_inl, extents, meta, out);
}